// Round 1
// 593.558 us; speedup vs baseline: 1.0071x; 1.0071x over previous
//
#include <hip/hip_runtime.h>

// Sinkhorn with ragged masks, factorized into scaling vectors:
//   A = s + EPS (inside block), R/C scaling vectors.
//   col update: C[j] = 1 / sum_{i<nr} A[i,j]*R[i]
//   row update: R[i] = 1 / sum_{j<nc} A[i,j]*C[j]
// 10 alternating updates starting with col (R=1): col is fused into prep
// (exact fp32), the last row update is fused with the output scale (exact
// fp32 from s). Middle 8 passes read a fp16 copy H of A (L3-resident)
// staged in the lower half of d_out.
// v2: row pass = 8 interleaved rows/wave with C staged in registers
// (latency/ILP fix); col pass computes C directly per 64-col stripe
// (rcp+mask in-kernel, no partials/creduce round trip).

#define BB 64
#define NN 1024
#define MM 1024
#define EPS 1e-4f

typedef _Float16 half_t;
typedef __attribute__((ext_vector_type(4))) _Float16 half4_t;
typedef __attribute__((ext_vector_type(8))) _Float16 half8_t;
typedef __attribute__((ext_vector_type(4))) float float4_t;

// prep: H=(half)(s+eps) + fp32 partial col sums (first col update, R=1).
// grid (8 stripes of 128 cols, 8 row-chunks of 128, BB), block 256.
__global__ __launch_bounds__(256) void prep_kernel(
    const float* __restrict__ s, const int* __restrict__ nrows,
    const int* __restrict__ ncols, half_t* __restrict__ H,
    float* __restrict__ P) {
  int b = blockIdx.z, rc = blockIdx.y, stripe = blockIdx.x;
  int nr = nrows[b], nc = ncols[b];
  float* Pp = P + ((size_t)rc * BB + b) * MM + stripe * 128;
  if (stripe * 128 >= nc) {  // stripe fully masked: zero partials
    if (threadIdx.x < 128) Pp[threadIdx.x] = 0.f;
    return;
  }
  int tc = threadIdx.x & 31, tr = threadIdx.x >> 5;
  int j0 = stripe * 128 + tc * 4;
  const float* sp = s + (size_t)b * NN * MM + j0;
  half_t* hp = H + (size_t)b * NN * MM + j0;
  float4_t acc = {0.f, 0.f, 0.f, 0.f};
  int base = rc * 128;
#pragma unroll
  for (int it = 0; it < 16; it++) {
    int i = base + it * 8 + tr;
    if (i < nr) {
      float4_t v = *(const float4_t*)(sp + (size_t)i * MM);
      v.x += EPS; v.y += EPS; v.z += EPS; v.w += EPS;
      half4_t h = {(half_t)v.x, (half_t)v.y, (half_t)v.z, (half_t)v.w};
      *(half4_t*)(hp + (size_t)i * MM) = h;
      acc.x += v.x; acc.y += v.y; acc.z += v.z; acc.w += v.w;
    }
  }
  __shared__ float lds[8][128];
  *(float4_t*)&lds[tr][tc * 4] = acc;
  __syncthreads();
  if (threadIdx.x < 128) {
    float s0 = 0.f;
#pragma unroll
    for (int k = 0; k < 8; k++) s0 += lds[k][threadIdx.x];
    Pp[threadIdx.x] = s0;
  }
}

// fold 8 prep partials -> C[j] = (j<nc) ? 1/sum : 0.  grid (4, BB), block 256.
__global__ __launch_bounds__(256) void creduce_kernel(
    const float* __restrict__ P, const int* __restrict__ ncols,
    float* __restrict__ C) {
  int b = blockIdx.y;
  int j = blockIdx.x * 256 + threadIdx.x;
  int nc = ncols[b];
  float s0 = 0.f;
#pragma unroll
  for (int k = 0; k < 8; k++) s0 += P[((size_t)k * BB + b) * MM + j];
  C[b * MM + j] = (j < nc) ? 1.f / s0 : 0.f;
}

// row update: R[i] = 1/sum_{j<nc} H[i,j]*C[j].
// 8 interleaved rows per wave (i = rg + 128*r), C staged in 16 registers
// once per wave. grid (32, BB), block 256 (4 waves).
__global__ __launch_bounds__(256) void row_kernel(
    const half_t* __restrict__ H, const int* __restrict__ nrows,
    const int* __restrict__ ncols, const float* __restrict__ C,
    float* __restrict__ R) {
  int b = blockIdx.y;
  int nr = nrows[b], nc = ncols[b];
  int l = threadIdx.x & 63;
  int rg = blockIdx.x * 4 + (threadIdx.x >> 6);  // [0,128), wave-uniform
  const float* Cp = C + b * MM;
  // lane l owns cols [l*8, l*8+8) and [512+l*8, 512+l*8+8).
  // nc >= 512 always, so chunk 0 is never masked; C[j>=nc]==0 masks tails.
  float4_t c00 = *(const float4_t*)(Cp + l * 8);
  float4_t c01 = *(const float4_t*)(Cp + l * 8 + 4);
  float4_t c10 = *(const float4_t*)(Cp + 512 + l * 8);
  float4_t c11 = *(const float4_t*)(Cp + 512 + l * 8 + 4);
  bool hi = (512 + l * 8) < nc;  // skip loads of undefined H past align128(nc)
  const half_t* hp = H + (size_t)b * NN * MM + l * 8;
#pragma unroll
  for (int r = 0; r < 8; r++) {
    int i = rg + (r << 7);
    if (i < nr) {  // wave-uniform; R[i>=nr] never read
      const half_t* hr = hp + (size_t)i * MM;
      half8_t h0 = *(const half8_t*)hr;
      float acc = (float)h0[0] * c00.x + (float)h0[1] * c00.y +
                  (float)h0[2] * c00.z + (float)h0[3] * c00.w +
                  (float)h0[4] * c01.x + (float)h0[5] * c01.y +
                  (float)h0[6] * c01.z + (float)h0[7] * c01.w;
      if (hi) {
        half8_t h1 = *(const half8_t*)(hr + 512);
        acc += (float)h1[0] * c10.x + (float)h1[1] * c10.y +
               (float)h1[2] * c10.z + (float)h1[3] * c10.w +
               (float)h1[4] * c11.x + (float)h1[5] * c11.y +
               (float)h1[6] * c11.z + (float)h1[7] * c11.w;
      }
#pragma unroll
      for (int off = 32; off > 0; off >>= 1) acc += __shfl_xor(acc, off, 64);
      if (l == 0) R[b * NN + i] = 1.f / acc;
    }
  }
}

// col update: C[j] = (j<nc) ? 1/sum_{i<nr} H[i,j]*R[i] : 0, computed
// directly (no partials, no creduce). Block owns a full 64-col x 1024-row
// stripe. grid (16, BB), block 256.
__global__ __launch_bounds__(256) void col_kernel(
    const half_t* __restrict__ H, const int* __restrict__ nrows,
    const int* __restrict__ ncols, const float* __restrict__ R,
    float* __restrict__ C) {
  int b = blockIdx.y;
  int j0 = blockIdx.x * 64;
  int nr = nrows[b], nc = ncols[b];
  if (j0 >= nc) {  // fully masked stripe
    if (threadIdx.x < 64) C[b * MM + j0 + threadIdx.x] = 0.f;
    return;
  }
  int tc = threadIdx.x & 7, tr = threadIdx.x >> 3;  // 8 col-groups x 32 rows
  const half_t* hp = H + (size_t)b * NN * MM + j0 + tc * 8;
  const float* Rp = R + b * NN;
  float acc[8] = {0.f, 0.f, 0.f, 0.f, 0.f, 0.f, 0.f, 0.f};
#pragma unroll 4
  for (int it = 0; it < 32; it++) {
    int i = (it << 5) + tr;
    if (i < nr) {
      half8_t h = *(const half8_t*)(hp + (size_t)i * MM);
      float r = Rp[i];
#pragma unroll
      for (int k = 0; k < 8; k++) acc[k] += (float)h[k] * r;
    }
  }
  __shared__ float lds[32][64];
#pragma unroll
  for (int k = 0; k < 8; k++) lds[tr][tc * 8 + k] = acc[k];
  __syncthreads();
  if (threadIdx.x < 64) {
    float s0 = 0.f;
#pragma unroll
    for (int k = 0; k < 32; k++) s0 += lds[k][threadIdx.x];
    int j = j0 + threadIdx.x;
    C[b * MM + j] = (j < nc) ? 1.f / s0 : 0.f;
  }
}

// last row update fused with output: row sum from exact fp32 s (held in
// registers), then out = (s+eps)*C*(1/rowsum); zeros for i>=nr / j>=nc.
// One wave per row, grid (NN/4, BB), block 256.
__global__ __launch_bounds__(256) void final_kernel(
    const float* __restrict__ s, const int* __restrict__ nrows,
    const int* __restrict__ ncols, const float* __restrict__ C,
    float* __restrict__ out) {
  int b = blockIdx.y;
  int nr = nrows[b], nc = ncols[b];
  int w = threadIdx.x >> 6, l = threadIdx.x & 63;
  int i = blockIdx.x * 4 + w;
  float* op = out + ((size_t)b * NN + i) * MM;
  float4_t z = {0.f, 0.f, 0.f, 0.f};
  if (i >= nr) {
#pragma unroll
    for (int ch = 0; ch < 4; ch++) *(float4_t*)(op + ch * 256 + l * 4) = z;
    return;
  }
  const float* sp = s + ((size_t)b * NN + i) * MM;
  const float* Cp = C + b * MM;
  float4_t sv[4], cv[4];
  float acc = 0.f;
  int nch = (nc + 255) >> 8;
#pragma unroll
  for (int ch = 0; ch < 4; ch++) {
    if (ch < nch) {
      float4_t v = *(const float4_t*)(sp + ch * 256 + l * 4);
      v.x += EPS; v.y += EPS; v.z += EPS; v.w += EPS;
      sv[ch] = v;
      float4_t c = *(const float4_t*)(Cp + ch * 256 + l * 4);
      cv[ch] = c;
      acc += v.x * c.x + v.y * c.y + v.z * c.z + v.w * c.w;
    }
  }
#pragma unroll
  for (int off = 32; off > 0; off >>= 1) acc += __shfl_xor(acc, off, 64);
  float r = 1.f / acc;
#pragma unroll
  for (int ch = 0; ch < 4; ch++) {
    if (ch < nch) {
      float4_t o;
      o.x = sv[ch].x * cv[ch].x * r;
      o.y = sv[ch].y * cv[ch].y * r;
      o.z = sv[ch].z * cv[ch].z * r;
      o.w = sv[ch].w * cv[ch].w * r;
      *(float4_t*)(op + ch * 256 + l * 4) = o;
    } else {
      *(float4_t*)(op + ch * 256 + l * 4) = z;
    }
  }
}

extern "C" void kernel_launch(void* const* d_in, const int* in_sizes, int n_in,
                              void* d_out, int out_size, void* d_ws,
                              size_t ws_size, hipStream_t stream) {
  const float* s = (const float*)d_in[0];
  const int* nrows = (const int*)d_in[1];
  const int* ncols = (const int*)d_in[2];
  float* out = (float*)d_out;
  half_t* H = (half_t*)d_out;  // fp16 A in lower 128MB of d_out; final pass
                               // never reads H, so out-writes can't race it
  float* R = (float*)d_ws;                 // [BB*NN]
  float* C = R + BB * NN;                  // [BB*MM]
  float* P = C + BB * MM;                  // [8][BB][MM] partial col sums

  dim3 pgrid(8, 8, BB);    // 4096 blocks
  dim3 dgrid(4, BB);       // creduce (once, after prep)
  dim3 rgrid(32, BB);      // 2048 blocks, 8 rows/wave
  dim3 cgrid(16, BB);      // 1024 blocks, 64-col stripes
  dim3 fgrid(NN / 4, BB);  // 16384 blocks

  prep_kernel<<<pgrid, 256, 0, stream>>>(s, nrows, ncols, H, P);
  creduce_kernel<<<dgrid, 256, 0, stream>>>(P, ncols, C);
  for (int t = 0; t < 4; t++) {
    row_kernel<<<rgrid, 256, 0, stream>>>(H, nrows, ncols, C, R);
    col_kernel<<<cgrid, 256, 0, stream>>>(H, nrows, ncols, R, C);
  }
  final_kernel<<<fgrid, 256, 0, stream>>>(s, nrows, ncols, C, out);
}

// Round 2
// 566.426 us; speedup vs baseline: 1.0553x; 1.0479x over previous
//
#include <hip/hip_runtime.h>

// Sinkhorn with ragged masks, factorized into scaling vectors:
//   A = s + EPS (inside block), R/C scaling vectors.
//   col update: C[j] = 1 / sum_{i<nr} A[i,j]*R[i]
//   row update: R[i] = 1 / sum_{j<nc} A[i,j]*C[j]
// 10 alternating updates starting with col: col#1 fused into prep (exact
// fp32), last row update fused with output scale (exact fp32 from s).
// Middle 8 updates run on a fp16 copy H of A staged in the lower half of
// d_out.
// v3: the middle is 4 FUSED passes — one sweep of H computes the row
// update (dot with C, R=1/acc) and immediately re-uses the H registers to
// accumulate col partials H*R. H is read 4x instead of 8x (~537 MB less
// traffic). R never goes to global memory.

#define BB 64
#define NN 1024
#define MM 1024
#define EPS 1e-4f

typedef _Float16 half_t;
typedef __attribute__((ext_vector_type(4))) _Float16 half4_t;
typedef __attribute__((ext_vector_type(8))) _Float16 half8_t;
typedef __attribute__((ext_vector_type(4))) float float4_t;
typedef __attribute__((ext_vector_type(2))) float float2_t;

// prep: H=(half)(s+eps) + fp32 partial col sums (first col update, R=1).
// grid (8 stripes of 128 cols, 8 row-chunks of 128, BB), block 256.
__global__ __launch_bounds__(256) void prep_kernel(
    const float* __restrict__ s, const int* __restrict__ nrows,
    const int* __restrict__ ncols, half_t* __restrict__ H,
    float* __restrict__ P) {
  int b = blockIdx.z, rc = blockIdx.y, stripe = blockIdx.x;
  int nr = nrows[b], nc = ncols[b];
  float* Pp = P + ((size_t)rc * BB + b) * MM + stripe * 128;
  if (stripe * 128 >= nc) {  // stripe fully masked: zero partials
    if (threadIdx.x < 128) Pp[threadIdx.x] = 0.f;
    return;
  }
  int tc = threadIdx.x & 31, tr = threadIdx.x >> 5;
  int j0 = stripe * 128 + tc * 4;
  const float* sp = s + (size_t)b * NN * MM + j0;
  half_t* hp = H + (size_t)b * NN * MM + j0;
  float4_t acc = {0.f, 0.f, 0.f, 0.f};
  int base = rc * 128;
#pragma unroll
  for (int it = 0; it < 16; it++) {
    int i = base + it * 8 + tr;
    if (i < nr) {
      float4_t v = *(const float4_t*)(sp + (size_t)i * MM);
      v.x += EPS; v.y += EPS; v.z += EPS; v.w += EPS;
      half4_t h = {(half_t)v.x, (half_t)v.y, (half_t)v.z, (half_t)v.w};
      *(half4_t*)(hp + (size_t)i * MM) = h;
      acc.x += v.x; acc.y += v.y; acc.z += v.z; acc.w += v.w;
    }
  }
  __shared__ float lds[8][128];
  *(float4_t*)&lds[tr][tc * 4] = acc;
  __syncthreads();
  if (threadIdx.x < 128) {
    float s0 = 0.f;
#pragma unroll
    for (int k = 0; k < 8; k++) s0 += lds[k][threadIdx.x];
    Pp[threadIdx.x] = s0;
  }
}

// fold 8 partials -> C[j] = (j<nc) ? 1/sum : 0.  grid (4, BB), block 256.
__global__ __launch_bounds__(256) void creduce_kernel(
    const float* __restrict__ P, const int* __restrict__ ncols,
    float* __restrict__ C) {
  int b = blockIdx.y;
  int j = blockIdx.x * 256 + threadIdx.x;
  int nc = ncols[b];
  float s0 = 0.f;
#pragma unroll
  for (int k = 0; k < 8; k++) s0 += P[((size_t)k * BB + b) * MM + j];
  C[b * MM + j] = (j < nc) ? 1.f / s0 : 0.f;
}

// fused row+col update: one sweep of H. Per row i (< nr):
//   acc = sum_j H[i,j]*C[j];  R = 1/acc  (row update, in-register)
//   colacc[j] += H[i,j]*R                (col partial, same H registers)
// Lane l owns cols [l*8,l*8+8) and [512+l*8,512+l*8+8); nc>=512 so chunk0
// is always valid; hi chunk skipped when beyond nc (C[j>=nc]==0 masks
// in-chunk tails). Wave w of 8 handles rows chunk*128 + w + 8*r.
// grid (8 row-chunks, BB), block 512. P partials in the prep layout.
__global__ __launch_bounds__(512) void fused_kernel(
    const half_t* __restrict__ H, const int* __restrict__ nrows,
    const int* __restrict__ ncols, const float* __restrict__ C,
    float* __restrict__ P) {
  int b = blockIdx.y, ch = blockIdx.x;
  int nr = nrows[b], nc = ncols[b];
  int l = threadIdx.x & 63, w = threadIdx.x >> 6;
  const float* Cp = C + b * MM;
  float c0[8], c1[8];
  *(float4_t*)&c0[0] = *(const float4_t*)(Cp + l * 8);
  *(float4_t*)&c0[4] = *(const float4_t*)(Cp + l * 8 + 4);
  *(float4_t*)&c1[0] = *(const float4_t*)(Cp + 512 + l * 8);
  *(float4_t*)&c1[4] = *(const float4_t*)(Cp + 512 + l * 8 + 4);
  bool hi = (512 + l * 8) < nc;  // H defined up to ceil128(nc); 8-aligned ok
  const half_t* hp = H + (size_t)b * NN * MM + l * 8;
  float a0[8] = {0.f, 0.f, 0.f, 0.f, 0.f, 0.f, 0.f, 0.f};
  float a1[8] = {0.f, 0.f, 0.f, 0.f, 0.f, 0.f, 0.f, 0.f};
  int rbase = ch * 128 + w;
#pragma unroll 4
  for (int r = 0; r < 16; r++) {
    int i = rbase + (r << 3);
    if (i < nr) {  // wave-uniform
      const half_t* hr = hp + (size_t)i * MM;
      half8_t h0 = *(const half8_t*)hr;
      float f0[8];
#pragma unroll
      for (int k = 0; k < 8; k++) f0[k] = (float)h0[k];
      float acc = f0[0] * c0[0] + f0[1] * c0[1] + f0[2] * c0[2] +
                  f0[3] * c0[3] + f0[4] * c0[4] + f0[5] * c0[5] +
                  f0[6] * c0[6] + f0[7] * c0[7];
      float f1[8];
      if (hi) {
        half8_t h1 = *(const half8_t*)(hr + 512);
#pragma unroll
        for (int k = 0; k < 8; k++) f1[k] = (float)h1[k];
        acc += f1[0] * c1[0] + f1[1] * c1[1] + f1[2] * c1[2] +
               f1[3] * c1[3] + f1[4] * c1[4] + f1[5] * c1[5] +
               f1[6] * c1[6] + f1[7] * c1[7];
      }
#pragma unroll
      for (int off = 32; off > 0; off >>= 1) acc += __shfl_xor(acc, off, 64);
      float rv = 1.f / acc;
#pragma unroll
      for (int k = 0; k < 8; k++) a0[k] += f0[k] * rv;
      if (hi) {
#pragma unroll
        for (int k = 0; k < 8; k++) a1[k] += f1[k] * rv;
      }
    }
  }
  // block reduce: 8 waves hold partials for the same lane-owned cols.
  __shared__ float lds[8][MM];
#pragma unroll
  for (int k = 0; k < 8; k++) lds[w][l * 8 + k] = a0[k];
#pragma unroll
  for (int k = 0; k < 8; k++) lds[w][512 + l * 8 + k] = a1[k];
  __syncthreads();
  int t = threadIdx.x;
  float s0 = 0.f, s1 = 0.f;
#pragma unroll
  for (int k = 0; k < 8; k++) {
    s0 += lds[k][t * 2];
    s1 += lds[k][t * 2 + 1];
  }
  float2_t o = {s0, s1};
  *(float2_t*)(P + ((size_t)ch * BB + b) * MM + t * 2) = o;
}

// last row update fused with output: row sum from exact fp32 s (held in
// registers), then out = (s+eps)*C*(1/rowsum); zeros for i>=nr / j>=nc.
// One wave per row, grid (NN/4, BB), block 256.
__global__ __launch_bounds__(256) void final_kernel(
    const float* __restrict__ s, const int* __restrict__ nrows,
    const int* __restrict__ ncols, const float* __restrict__ C,
    float* __restrict__ out) {
  int b = blockIdx.y;
  int nr = nrows[b], nc = ncols[b];
  int w = threadIdx.x >> 6, l = threadIdx.x & 63;
  int i = blockIdx.x * 4 + w;
  float* op = out + ((size_t)b * NN + i) * MM;
  float4_t z = {0.f, 0.f, 0.f, 0.f};
  if (i >= nr) {
#pragma unroll
    for (int ch = 0; ch < 4; ch++) *(float4_t*)(op + ch * 256 + l * 4) = z;
    return;
  }
  const float* sp = s + ((size_t)b * NN + i) * MM;
  const float* Cp = C + b * MM;
  float4_t sv[4], cv[4];
  float acc = 0.f;
  int nch = (nc + 255) >> 8;
#pragma unroll
  for (int ch = 0; ch < 4; ch++) {
    if (ch < nch) {
      float4_t v = *(const float4_t*)(sp + ch * 256 + l * 4);
      v.x += EPS; v.y += EPS; v.z += EPS; v.w += EPS;
      sv[ch] = v;
      float4_t c = *(const float4_t*)(Cp + ch * 256 + l * 4);
      cv[ch] = c;
      acc += v.x * c.x + v.y * c.y + v.z * c.z + v.w * c.w;
    }
  }
#pragma unroll
  for (int off = 32; off > 0; off >>= 1) acc += __shfl_xor(acc, off, 64);
  float r = 1.f / acc;
#pragma unroll
  for (int ch = 0; ch < 4; ch++) {
    if (ch < nch) {
      float4_t o;
      o.x = sv[ch].x * cv[ch].x * r;
      o.y = sv[ch].y * cv[ch].y * r;
      o.z = sv[ch].z * cv[ch].z * r;
      o.w = sv[ch].w * cv[ch].w * r;
      *(float4_t*)(op + ch * 256 + l * 4) = o;
    } else {
      *(float4_t*)(op + ch * 256 + l * 4) = z;
    }
  }
}

extern "C" void kernel_launch(void* const* d_in, const int* in_sizes, int n_in,
                              void* d_out, int out_size, void* d_ws,
                              size_t ws_size, hipStream_t stream) {
  const float* s = (const float*)d_in[0];
  const int* nrows = (const int*)d_in[1];
  const int* ncols = (const int*)d_in[2];
  float* out = (float*)d_out;
  half_t* H = (half_t*)d_out;  // fp16 A in lower 128MB of d_out; final pass
                               // never reads H, so out-writes can't race it
  float* C = (float*)d_ws;                 // [BB*MM]
  float* P = C + BB * MM;                  // [8][BB][MM] partial col sums

  dim3 pgrid(8, 8, BB);    // prep: 4096 blocks
  dim3 dgrid(4, BB);       // creduce
  dim3 ugrid(8, BB);       // fused: 512 blocks x 512 threads
  dim3 fgrid(NN / 4, BB);  // final: 16384 blocks

  prep_kernel<<<pgrid, 256, 0, stream>>>(s, nrows, ncols, H, P);
  creduce_kernel<<<dgrid, 256, 0, stream>>>(P, ncols, C);
  for (int t = 0; t < 4; t++) {
    fused_kernel<<<ugrid, 512, 0, stream>>>(H, nrows, ncols, C, P);
    creduce_kernel<<<dgrid, 256, 0, stream>>>(P, ncols, C);
  }
  final_kernel<<<fgrid, 256, 0, stream>>>(s, nrows, ncols, C, out);
}